// Round 6
// baseline (300.990 us; speedup 1.0000x reference)
//
#include <hip/hip_runtime.h>
#include <hip/hip_bf16.h>

// CausalSelfAttention  B=1, T=4096, C=768, H=12, hd=64
// Round 20: R19 post-mortem: nothing saturated (MFMA 23%, VALU 40%, LDS ~28%,
//   HBM 23%) -> flash is concurrency-starved: 256-thr blocks + 48KB LDS cap
//   residency at 12 waves/CU; barrier-locked chains leave ~1.7 live/SIMD.
//   Fix: 512-thread blocks, QBLK=256 (8 waves share each K/V tile; per-wave
//   body byte-identical) -> 24 waves/CU at same LDS, same total wave-iters.
//   D=12 split-k, 612 blocks (full-12 first), partial ws byte-identical to
//   R19's proven layout. gemms/prep unchanged.

#define T_SEQ 4096
#define C_DIM 768
#define C3    2304
#define NH    12
#define HD    64

typedef __attribute__((ext_vector_type(8))) short bf16x8;
typedef __attribute__((ext_vector_type(4))) short bf16x4;
typedef __attribute__((ext_vector_type(4))) float f32x4;

__device__ inline unsigned short f2bf(float f) {
  union { float f; unsigned u; } v; v.f = f;
  unsigned r = v.u + 0x7fff + ((v.u >> 16) & 1);  // RTNE
  return (unsigned short)(r >> 16);
}
__device__ inline unsigned short f2bf_trunc(float f) {
  union { float f; unsigned u; } v; v.f = f;
  return (unsigned short)(v.u >> 16);  // truncate: fine for P >= 0
}

__device__ inline void gl2lds16(const void* g, void* l) {
  __builtin_amdgcn_global_load_lds(
      (const __attribute__((address_space(1))) unsigned int*)g,
      (__attribute__((address_space(3))) unsigned int*)l, 16, 0, 0);
}

#if __has_builtin(__builtin_amdgcn_exp2f)
#define EXP2F(x) __builtin_amdgcn_exp2f(x)
#else
#define EXP2F(x) exp2f(x)
#endif

// ---------------------------------------------------------------------------
// fused prep: conv x->bf16 | transpose w_qkv | transpose w_proj
// ---------------------------------------------------------------------------
#define NB_CONV  (T_SEQ * C_DIM / 2048)          // 1536
#define NB_TQKV  ((C3 / 32) * (C_DIM / 32))      // 1728
#define NB_TPROJ ((C_DIM / 32) * (C_DIM / 32))   // 576

__global__ __launch_bounds__(256) void prep_fused(
    const float* __restrict__ x, const float* __restrict__ w_qkv,
    const float* __restrict__ w_proj, unsigned short* __restrict__ xb,
    unsigned short* __restrict__ wqkvT, unsigned short* __restrict__ wprojT) {
  __shared__ float t[32][33];
  const int b = blockIdx.x;
  const int tid = threadIdx.x;

  if (b < NB_CONV) {
    int i = (b * 256 + tid) * 8;
    float4 v0 = *(const float4*)(x + i);
    float4 v1 = *(const float4*)(x + i + 4);
    unsigned short o[8] = {f2bf(v0.x), f2bf(v0.y), f2bf(v0.z), f2bf(v0.w),
                           f2bf(v1.x), f2bf(v1.y), f2bf(v1.z), f2bf(v1.w)};
    *(uint4*)(xb + i) = *(uint4*)o;
    return;
  }
  const float* in;
  unsigned short* outT;
  int R, Cc, bi;
  if (b < NB_CONV + NB_TQKV) {
    in = w_qkv; outT = wqkvT; R = C_DIM; Cc = C3; bi = b - NB_CONV;
  } else {
    in = w_proj; outT = wprojT; R = C_DIM; Cc = C_DIM; bi = b - NB_CONV - NB_TQKV;
  }
  const int tx = tid & 31, ty = tid >> 5;
  const int c0 = (bi % (Cc / 32)) * 32, r0 = (bi / (Cc / 32)) * 32;
#pragma unroll
  for (int i = 0; i < 4; ++i) {
    int r = ty + i * 8;
    t[r][tx] = in[(size_t)(r0 + r) * Cc + c0 + tx];
  }
  __syncthreads();
#pragma unroll
  for (int i = 0; i < 4; ++i) {
    int c = ty + i * 8;
    outT[(size_t)(c0 + c) * R + r0 + tx] = f2bf(t[tx][c]);
  }
}

// ---------------------------------------------------------------------------
// gemm1: qkv = xb @ wqkvT^T + b_qkv; V blocks write k-permuted vTp directly.
// Q columns (n < 768) pre-scaled by 0.125*log2(e).
// ---------------------------------------------------------------------------
__global__ __launch_bounds__(256) void gemm_qkv(
    const unsigned short* __restrict__ A, const unsigned short* __restrict__ Bt,
    const float* __restrict__ bias, unsigned short* __restrict__ Cq,
    unsigned short* __restrict__ vTp, int M, int N, int K) {
  __shared__ unsigned short As[128 * 64];
  __shared__ unsigned short Bs[128 * 64];
  const int tid = threadIdx.x;
  const int wave = tid >> 6, lane = tid & 63;
  const int lo = lane & 15, g8 = lane >> 4;
  const int lo7 = lo & 7;
  const int wm = wave >> 1, wn = wave & 1;
  const int bm = blockIdx.y * 128, bn = blockIdx.x * 128;
  const int drow8 = lane >> 3;               // 0..7
  const int dslot = (lane & 7) * 8;
  const int dsrc = ((lane & 7) ^ drow8) * 8; // swizzled source chunk

  f32x4 acc[4][4];
#pragma unroll
  for (int mt = 0; mt < 4; ++mt)
#pragma unroll
    for (int nt = 0; nt < 4; ++nt) acc[mt][nt] = (f32x4){0.f, 0.f, 0.f, 0.f};

  const unsigned short* Abase = A + (size_t)bm * K;
  const unsigned short* Bbase = Bt + (size_t)bn * K;

  for (int k0 = 0; k0 < K; k0 += 64) {
    __syncthreads();
#pragma unroll
    for (int p = 0; p < 4; ++p) {
      const int r = p * 32 + wave * 8 + drow8;
      gl2lds16(Abase + (size_t)r * K + k0 + dsrc, As + r * 64 + dslot);
      gl2lds16(Bbase + (size_t)r * K + k0 + dsrc, Bs + r * 64 + dslot);
    }
    __syncthreads();

#pragma unroll
    for (int kk = 0; kk < 2; ++kk) {
      bf16x8 a[4], b[4];
#pragma unroll
      for (int mt = 0; mt < 4; ++mt)
        a[mt] = *(const bf16x8*)(
            As + (wm * 64 + mt * 16 + lo) * 64 + (((kk * 4 + g8) ^ lo7) * 8));
#pragma unroll
      for (int nt = 0; nt < 4; ++nt)
        b[nt] = *(const bf16x8*)(
            Bs + (wn * 64 + nt * 16 + lo) * 64 + (((kk * 4 + g8) ^ lo7) * 8));
#pragma unroll
      for (int mt = 0; mt < 4; ++mt)
#pragma unroll
        for (int nt = 0; nt < 4; ++nt)
          acc[mt][nt] = __builtin_amdgcn_mfma_f32_16x16x32_bf16(a[mt], b[nt], acc[mt][nt], 0, 0, 0);
    }
  }

  if (bn < 2 * C_DIM) {
    const float sc = (bn < C_DIM) ? 0.18033688011112042f : 1.0f;  // 0.125*log2e
#pragma unroll
    for (int nt = 0; nt < 4; ++nt) {
      const int n = bn + wn * 64 + nt * 16 + lo;
      const float bv = bias[n];
#pragma unroll
      for (int mt = 0; mt < 4; ++mt)
#pragma unroll
        for (int r = 0; r < 4; ++r) {
          const int m = bm + wm * 64 + mt * 16 + g8 * 4 + r;
          Cq[(size_t)m * C3 + n] = f2bf((acc[mt][nt][r] + bv) * sc);
        }
    }
  } else {
#pragma unroll
    for (int nt = 0; nt < 4; ++nt) {
      const int n = bn + wn * 64 + nt * 16 + lo;
      const float bv = bias[n];
      unsigned short* row = vTp + (size_t)(n - 2 * C_DIM) * T_SEQ;
#pragma unroll
      for (int mt = 0; mt < 4; ++mt) {
        const int mbase = (bm + wm * 64 + mt * 16 + g8 * 4) & ~31;
        bf16x4 o4;
#pragma unroll
        for (int r = 0; r < 4; ++r) o4[r] = (short)f2bf(acc[mt][nt][r] + bv);
        *(bf16x4*)(row + mbase + 8 * g8 + 4 * (mt & 1)) = o4;
      }
    }
  }
}

// ---------------------------------------------------------------------------
// gemm2: bf16 MFMA GEMM, B^T input, fp32 out.
// ---------------------------------------------------------------------------
__global__ __launch_bounds__(256) void gemm_bt_mfma(
    const unsigned short* __restrict__ A, const unsigned short* __restrict__ Bt,
    const float* __restrict__ bias, float* __restrict__ C,
    int M, int N, int K) {
  __shared__ unsigned short As[128 * 64];
  __shared__ unsigned short Bs[128 * 64];
  const int tid = threadIdx.x;
  const int wave = tid >> 6, lane = tid & 63;
  const int lo = lane & 15, g8 = lane >> 4;
  const int lo7 = lo & 7;
  const int wm = wave >> 1, wn = wave & 1;
  const int bm = blockIdx.y * 128, bn = blockIdx.x * 128;
  const int drow8 = lane >> 3;
  const int dslot = (lane & 7) * 8;
  const int dsrc = ((lane & 7) ^ drow8) * 8;

  f32x4 acc[4][4];
#pragma unroll
  for (int mt = 0; mt < 4; ++mt)
#pragma unroll
    for (int nt = 0; nt < 4; ++nt) acc[mt][nt] = (f32x4){0.f, 0.f, 0.f, 0.f};

  const unsigned short* Abase = A + (size_t)bm * K;
  const unsigned short* Bbase = Bt + (size_t)bn * K;

  for (int k0 = 0; k0 < K; k0 += 64) {
    __syncthreads();
#pragma unroll
    for (int p = 0; p < 4; ++p) {
      const int r = p * 32 + wave * 8 + drow8;
      gl2lds16(Abase + (size_t)r * K + k0 + dsrc, As + r * 64 + dslot);
      gl2lds16(Bbase + (size_t)r * K + k0 + dsrc, Bs + r * 64 + dslot);
    }
    __syncthreads();

#pragma unroll
    for (int kk = 0; kk < 2; ++kk) {
      bf16x8 a[4], b[4];
#pragma unroll
      for (int mt = 0; mt < 4; ++mt)
        a[mt] = *(const bf16x8*)(
            As + (wm * 64 + mt * 16 + lo) * 64 + (((kk * 4 + g8) ^ lo7) * 8));
#pragma unroll
      for (int nt = 0; nt < 4; ++nt)
        b[nt] = *(const bf16x8*)(
            Bs + (wn * 64 + nt * 16 + lo) * 64 + (((kk * 4 + g8) ^ lo7) * 8));
#pragma unroll
      for (int mt = 0; mt < 4; ++mt)
#pragma unroll
        for (int nt = 0; nt < 4; ++nt)
          acc[mt][nt] = __builtin_amdgcn_mfma_f32_16x16x32_bf16(a[mt], b[nt], acc[mt][nt], 0, 0, 0);
    }
  }

#pragma unroll
  for (int nt = 0; nt < 4; ++nt) {
    const int n = bn + wn * 64 + nt * 16 + lo;
    const float bv = bias[n];
#pragma unroll
    for (int mt = 0; mt < 4; ++mt)
#pragma unroll
      for (int r = 0; r < 4; ++r) {
        const int m = bm + wm * 64 + mt * 16 + g8 * 4 + r;
        C[(size_t)m * N + n] = acc[mt][nt][r] + bv;
      }
  }
}

// ---------------------------------------------------------------------------
// flash v18: QBLK=256, 512 threads (8 waves x 32 q-rows), KVBLK=64,
// triple-buffer + counted vmcnt. 16 q-blocks/head; q-block qt has
// n = 4qt+4 k-tiles, chunked at D=12: nc(qt) = qt/3+1, 51 recs/head,
// 612 blocks (480 full-12 launched first, then 8-tails, then 4-tails).
// Partial record = 256x64 fp32 (Po bytes identical to R19's proven ws).
// ---------------------------------------------------------------------------
#define NRECH  51                          // records per head
#define PO_REC (256 * 64)
#define KSTEP  (64 * C3)                   // shorts per k-tile (K stream)

__device__ inline int s_pref(int qt) {     // S(qt) = sum_{q<qt} (q/3+1)
  const int A = qt / 3, B = qt - 3 * A;
  return qt + 3 * A * (A - 1) / 2 + A * B;
}

__global__ __launch_bounds__(512, 6) void flash_attn_qb256(
    const unsigned short* __restrict__ qkv,   // [T][2304] bf16 (Qs,K valid)
    const unsigned short* __restrict__ vTp,   // [768][T] bf16, k-permuted
    float* __restrict__ Po, float* __restrict__ Pl) {
  __shared__ unsigned short Ks[3][64 * 64];
  __shared__ unsigned short Vs[3][64 * 64];

  // longest-first decode of blockIdx.x -> (h, qt, c, k0, T)
  const int u = blockIdx.x;
  int h, qt, c, k0, T;
  if (u < 480) {                       // full-12 chunks
    h = u / 40;
    const int w40 = u % 40;
    qt = 2; c = 0;
    for (int q = 15; q >= 2; --q) {
      const int A = q / 3, B = q - 3 * A;          // F12(q) = sum floor(m/3)
      const int F = 3 * A * (A - 1) / 2 + A * (B + 1);
      if (w40 >= F) { qt = q; c = w40 - F; break; }
    }
    k0 = 12 * c; T = 12;
  } else if (u < 540) {                // 8-tails (qt = 3e+1)
    const int v = u - 480; h = v / 5; const int e = v % 5;
    qt = 3 * e + 1; c = e; k0 = 12 * e; T = 8;
  } else {                             // 4-tails (qt = 3e)
    const int v = u - 540; h = v / 6; const int e = v % 6;
    qt = 3 * e; c = e; k0 = 12 * e; T = 4;
  }
  const int rec = h * NRECH + s_pref(qt) + c;
  const int qt4 = 4 * qt;              // first diagonal k-tile

  const int tid = threadIdx.x;
  const int w = tid >> 6;              // 0..7
  const int lane = tid & 63;
  const int lo = lane & 15;
  const int g = lane >> 4;
  const int lo7 = lo & 7;

  const unsigned short* Kg = qkv + C_DIM + h * HD;           // row stride C3
  const unsigned short* Vg = vTp + (size_t)(h * HD) * T_SEQ; // row stride T_SEQ

  const int drow = tid >> 3;                    // 0..63 (full tile row)
  const int dslot = (tid & 7) * 8;
  const int dsrc = ((tid & 7) ^ (drow & 7)) * 8;

  // Q B-frags: 2 q-halves x 2 d-halves (Q pre-scaled in gemm1). Issued
  // before the DMAs; in-order vmcnt retirement => vmcnt(2) covers them.
  const int qw0 = w * 32 + lo;                  // local q-row, + qh*16
  bf16x8 qb[2][2];
#pragma unroll
  for (int qh = 0; qh < 2; ++qh)
#pragma unroll
    for (int dh = 0; dh < 2; ++dh)
      qb[qh][dh] = *(const bf16x8*)(
          qkv + (size_t)(qt * 256 + qw0 + qh * 16) * C3 + h * HD + dh * 32 + g * 8);

  // stride-increment DMA pointers (one K + one V DMA per thread per tile)
  const unsigned short* pK = Kg + (size_t)(k0 * 64 + drow) * C3 + dsrc;
  const unsigned short* pV = Vg + (size_t)drow * T_SEQ + k0 * 64 + dsrc;

  auto stage = [&](int buf) __attribute__((always_inline)) {
    gl2lds16(pK, Ks[buf] + drow * 64 + dslot);
    gl2lds16(pV, Vs[buf] + drow * 64 + dslot);
    pK += KSTEP; pV += 64;
  };

  bf16x8 onesb;
#pragma unroll
  for (int e = 0; e < 8; ++e) onesb[e] = (short)0x3F80;  // bf16 1.0

  // prologue: distance-2 pipeline (T >= 4 always)
  stage(0);
  stage(1);
  asm volatile("s_waitcnt vmcnt(2)" ::: "memory");  // qb + tile0 done
  __builtin_amdgcn_s_barrier();

  f32x4 o_acc[2][4];
  f32x4 lacc[2];
#pragma unroll
  for (int qh = 0; qh < 2; ++qh) {
    lacc[qh] = (f32x4){0.f, 0.f, 0.f, 0.f};
#pragma unroll
    for (int dt = 0; dt < 4; ++dt) o_acc[qh][dt] = (f32x4){0.f, 0.f, 0.f, 0.f};
  }

  int ic = 0, iw = 2;
  int ktc = k0;
  for (int t = 0; t < T; ++t) {
    if (t + 2 < T) stage(iw);
    const unsigned short* Kc = Ks[ic];
    const unsigned short* Vc = Vs[ic];

    // St = K @ Q^T  (scale folded into Q); K-frag shared by both q-halves
    f32x4 st[2][4];
#pragma unroll
    for (int qh = 0; qh < 2; ++qh)
#pragma unroll
      for (int mt = 0; mt < 4; ++mt) st[qh][mt] = (f32x4){0.f, 0.f, 0.f, 0.f};
    __builtin_amdgcn_s_setprio(1);
#pragma unroll
    for (int mt = 0; mt < 4; ++mt)
#pragma unroll
      for (int dh = 0; dh < 2; ++dh) {
        bf16x8 a = *(const bf16x8*)(
            Kc + (mt * 16 + lo) * 64 + (((dh * 4 + g) ^ lo7) * 8));
#pragma unroll
        for (int qh = 0; qh < 2; ++qh)
          st[qh][mt] = __builtin_amdgcn_mfma_f32_16x16x32_bf16(
              a, qb[qh][dh], st[qh][mt], 0, 0, 0);
      }
    __builtin_amdgcn_s_setprio(0);

    // causal mask: diagonal k-tiles (ktc in [4qt, 4qt+3])
    if (ktc >= qt4) {
      const int mb = (ktc - qt4) * 64;
#pragma unroll
      for (int qh = 0; qh < 2; ++qh) {
        const int qr = qw0 + qh * 16;
#pragma unroll
        for (int mt = 0; mt < 4; ++mt)
#pragma unroll
          for (int r = 0; r < 4; ++r)
            if (mb + mt * 16 + g * 4 + r > qr) st[qh][mt][r] = -1e30f;
      }
    }

    // no-max softmax: e = exp2(s)  (per-element trunc pack — proven codegen)
    bf16x8 pt[2][2];
#pragma unroll
    for (int qh = 0; qh < 2; ++qh)
#pragma unroll
      for (int kh = 0; kh < 2; ++kh)
#pragma unroll
        for (int jj = 0; jj < 4; ++jj) {
          float e0 = EXP2F(st[qh][kh * 2][jj]);
          float e1 = EXP2F(st[qh][kh * 2 + 1][jj]);
          pt[qh][kh][jj] = (short)f2bf_trunc(e0);
          pt[qh][kh][4 + jj] = (short)f2bf_trunc(e1);
        }

    __builtin_amdgcn_s_setprio(1);
    // l via ones-row MFMA (K-permutation invariant)
#pragma unroll
    for (int qh = 0; qh < 2; ++qh) {
      lacc[qh] = __builtin_amdgcn_mfma_f32_16x16x32_bf16(onesb, pt[qh][0], lacc[qh], 0, 0, 0);
      lacc[qh] = __builtin_amdgcn_mfma_f32_16x16x32_bf16(onesb, pt[qh][1], lacc[qh], 0, 0, 0);
    }
    // O^T += V^T @ P^T ; V-frag shared by both q-halves
#pragma unroll
    for (int dt = 0; dt < 4; ++dt)
#pragma unroll
      for (int kh = 0; kh < 2; ++kh) {
        bf16x8 av = *(const bf16x8*)(
            Vc + (dt * 16 + lo) * 64 + (((kh * 4 + g) ^ lo7) * 8));
#pragma unroll
        for (int qh = 0; qh < 2; ++qh)
          o_acc[qh][dt] = __builtin_amdgcn_mfma_f32_16x16x32_bf16(
              av, pt[qh][kh], o_acc[qh][dt], 0, 0, 0);
      }
    __builtin_amdgcn_s_setprio(0);

    // counted wait: tile t+1 complete; tile t+2's 2 DMAs stay in flight
    if (t + 2 < T)
      asm volatile("s_waitcnt vmcnt(2)" ::: "memory");
    else
      asm volatile("s_waitcnt vmcnt(0)" ::: "memory");
    __builtin_amdgcn_s_barrier();

    ic = (ic == 2) ? 0 : ic + 1;
    iw = (iw == 2) ? 0 : iw + 1;
    ++ktc;
  }

  // flush: unnormalized fp32 partials to record `rec`
  float* PoS = Po + (size_t)rec * PO_REC;
#pragma unroll
  for (int qh = 0; qh < 2; ++qh)
#pragma unroll
    for (int dt = 0; dt < 4; ++dt)
      *(f32x4*)(PoS + (qw0 + qh * 16) * 64 + dt * 16 + g * 4) = o_acc[qh][dt];
  if (g == 0) {
    float* PlS = Pl + (size_t)rec * 256;
#pragma unroll
    for (int qh = 0; qh < 2; ++qh) PlS[qw0 + qh * 16] = lacc[qh][0];
  }
}

// ---------------------------------------------------------------------------
// combine: out = (sum of recs) / (sum of l) -> bf16 [4096][768]
// records for (h,qt) are contiguous: [h*51 + S(qt), +nc) with nc = qt/3+1
// ---------------------------------------------------------------------------
__global__ __launch_bounds__(256) void combine_qb256(
    const float* __restrict__ Po, const float* __restrict__ Pl,
    unsigned short* __restrict__ out) {
  const int bid = blockIdx.x;          // 192 = NH*16
  const int h = bid >> 4, qt = bid & 15;
  const int nc = qt / 3 + 1;
  const int rec0 = h * NRECH + s_pref(qt);
  const int tid = threadIdx.x;
  const int q0 = tid >> 2;             // 0..63
  const int c0 = (tid & 3) * 16;
#pragma unroll
  for (int qq = 0; qq < 4; ++qq) {
    const int q = qq * 64 + q0;
    float l = 0.f;
    f32x4 acc[4];
#pragma unroll
    for (int e = 0; e < 4; ++e) acc[e] = (f32x4){0.f, 0.f, 0.f, 0.f};
    for (int c = 0; c < nc; ++c) {
      const size_t base = (size_t)(rec0 + c);
      l += Pl[base * 256 + q];
      const float* P = Po + base * PO_REC + q * 64 + c0;
#pragma unroll
      for (int e = 0; e < 4; ++e) acc[e] += *(const f32x4*)(P + e * 4);
    }
    const float inv = 1.0f / l;
    unsigned short ob[16];
#pragma unroll
    for (int e = 0; e < 4; ++e)
#pragma unroll
      for (int r = 0; r < 4; ++r) ob[e * 4 + r] = f2bf(acc[e][r] * inv);
    unsigned short* op = out + (size_t)(qt * 256 + q) * C_DIM + h * 64 + c0;
    *(uint4*)op = *(uint4*)ob;
    *(uint4*)(op + 8) = *(uint4*)(ob + 8);
  }
}

// ---------------------------------------------------------------------------
extern "C" void kernel_launch(void* const* d_in, const int* in_sizes, int n_in,
                              void* d_out, int out_size, void* d_ws, size_t ws_size,
                              hipStream_t stream) {
  const float* x      = (const float*)d_in[0];
  const float* w_qkv  = (const float*)d_in[1];
  const float* b_qkv  = (const float*)d_in[2];
  const float* w_proj = (const float*)d_in[3];
  const float* b_proj = (const float*)d_in[4];
  float* out = (float*)d_out;

  unsigned short* xb     = (unsigned short*)d_ws;               // [4096,768]
  unsigned short* wqkvT  = xb + (size_t)T_SEQ * C_DIM;          // [2304,768]
  unsigned short* wprojT = wqkvT + (size_t)C3 * C_DIM;          // [768,768]
  unsigned short* qkv    = wprojT + (size_t)C_DIM * C_DIM;      // [4096,2304]
  unsigned short* vTp    = qkv + (size_t)T_SEQ * C3;            // [768,4096]
  unsigned short* attnb  = xb;  // alias: xb is dead after gemm_qkv
  float* Po = (float*)(vTp + (size_t)C_DIM * T_SEQ);            // 612 recs fp32
  float* Pl = Po + (size_t)NH * NRECH * PO_REC;                 // 612*256 fp32

  prep_fused<<<NB_CONV + NB_TQKV + NB_TPROJ, 256, 0, stream>>>(
      x, w_qkv, w_proj, xb, wqkvT, wprojT);

  gemm_qkv<<<dim3(C3 / 128, T_SEQ / 128), 256, 0, stream>>>(
      xb, wqkvT, b_qkv, qkv, vTp, T_SEQ, C3, C_DIM);

  flash_attn_qb256<<<612, 512, 0, stream>>>(qkv, vTp, Po, Pl);

  combine_qb256<<<NH * 16, 256, 0, stream>>>(Po, Pl, attnb);

  gemm_bt_mfma<<<dim3(C_DIM / 128, T_SEQ / 128), 256, 0, stream>>>(
      attnb, wprojT, b_proj, out, T_SEQ, C_DIM, C_DIM);
}

// Round 7
// 183.785 us; speedup vs baseline: 1.6377x; 1.6377x over previous
//
#include <hip/hip_runtime.h>
#include <hip/hip_bf16.h>

// CausalSelfAttention  B=1, T=4096, C=768, H=12, hd=64
// Round 21: R20 post-mortem: __launch_bounds__(512,6) capped VGPR at 40 ->
//   spill cascade (413MB scratch WRITE, 247MB FETCH, flash 164us). The
//   512-thread QBLK=256 kernel itself PASSED correctness. This round is the
//   single-variable fix: launch_bounds(512,2) -> 256-VGPR budget, no spill,
//   natural ~76-100 VGPR -> 2-3 blocks/CU = 16-24 waves/CU (vs R19's 12).
//   Everything else byte-identical to R20 (decode, staging, body, combine).

#define T_SEQ 4096
#define C_DIM 768
#define C3    2304
#define NH    12
#define HD    64

typedef __attribute__((ext_vector_type(8))) short bf16x8;
typedef __attribute__((ext_vector_type(4))) short bf16x4;
typedef __attribute__((ext_vector_type(4))) float f32x4;

__device__ inline unsigned short f2bf(float f) {
  union { float f; unsigned u; } v; v.f = f;
  unsigned r = v.u + 0x7fff + ((v.u >> 16) & 1);  // RTNE
  return (unsigned short)(r >> 16);
}
__device__ inline unsigned short f2bf_trunc(float f) {
  union { float f; unsigned u; } v; v.f = f;
  return (unsigned short)(v.u >> 16);  // truncate: fine for P >= 0
}

__device__ inline void gl2lds16(const void* g, void* l) {
  __builtin_amdgcn_global_load_lds(
      (const __attribute__((address_space(1))) unsigned int*)g,
      (__attribute__((address_space(3))) unsigned int*)l, 16, 0, 0);
}

#if __has_builtin(__builtin_amdgcn_exp2f)
#define EXP2F(x) __builtin_amdgcn_exp2f(x)
#else
#define EXP2F(x) exp2f(x)
#endif

// ---------------------------------------------------------------------------
// fused prep: conv x->bf16 | transpose w_qkv | transpose w_proj
// ---------------------------------------------------------------------------
#define NB_CONV  (T_SEQ * C_DIM / 2048)          // 1536
#define NB_TQKV  ((C3 / 32) * (C_DIM / 32))      // 1728
#define NB_TPROJ ((C_DIM / 32) * (C_DIM / 32))   // 576

__global__ __launch_bounds__(256) void prep_fused(
    const float* __restrict__ x, const float* __restrict__ w_qkv,
    const float* __restrict__ w_proj, unsigned short* __restrict__ xb,
    unsigned short* __restrict__ wqkvT, unsigned short* __restrict__ wprojT) {
  __shared__ float t[32][33];
  const int b = blockIdx.x;
  const int tid = threadIdx.x;

  if (b < NB_CONV) {
    int i = (b * 256 + tid) * 8;
    float4 v0 = *(const float4*)(x + i);
    float4 v1 = *(const float4*)(x + i + 4);
    unsigned short o[8] = {f2bf(v0.x), f2bf(v0.y), f2bf(v0.z), f2bf(v0.w),
                           f2bf(v1.x), f2bf(v1.y), f2bf(v1.z), f2bf(v1.w)};
    *(uint4*)(xb + i) = *(uint4*)o;
    return;
  }
  const float* in;
  unsigned short* outT;
  int R, Cc, bi;
  if (b < NB_CONV + NB_TQKV) {
    in = w_qkv; outT = wqkvT; R = C_DIM; Cc = C3; bi = b - NB_CONV;
  } else {
    in = w_proj; outT = wprojT; R = C_DIM; Cc = C_DIM; bi = b - NB_CONV - NB_TQKV;
  }
  const int tx = tid & 31, ty = tid >> 5;
  const int c0 = (bi % (Cc / 32)) * 32, r0 = (bi / (Cc / 32)) * 32;
#pragma unroll
  for (int i = 0; i < 4; ++i) {
    int r = ty + i * 8;
    t[r][tx] = in[(size_t)(r0 + r) * Cc + c0 + tx];
  }
  __syncthreads();
#pragma unroll
  for (int i = 0; i < 4; ++i) {
    int c = ty + i * 8;
    outT[(size_t)(c0 + c) * R + r0 + tx] = f2bf(t[tx][c]);
  }
}

// ---------------------------------------------------------------------------
// gemm1: qkv = xb @ wqkvT^T + b_qkv; V blocks write k-permuted vTp directly.
// Q columns (n < 768) pre-scaled by 0.125*log2(e).
// ---------------------------------------------------------------------------
__global__ __launch_bounds__(256) void gemm_qkv(
    const unsigned short* __restrict__ A, const unsigned short* __restrict__ Bt,
    const float* __restrict__ bias, unsigned short* __restrict__ Cq,
    unsigned short* __restrict__ vTp, int M, int N, int K) {
  __shared__ unsigned short As[128 * 64];
  __shared__ unsigned short Bs[128 * 64];
  const int tid = threadIdx.x;
  const int wave = tid >> 6, lane = tid & 63;
  const int lo = lane & 15, g8 = lane >> 4;
  const int lo7 = lo & 7;
  const int wm = wave >> 1, wn = wave & 1;
  const int bm = blockIdx.y * 128, bn = blockIdx.x * 128;
  const int drow8 = lane >> 3;               // 0..7
  const int dslot = (lane & 7) * 8;
  const int dsrc = ((lane & 7) ^ drow8) * 8; // swizzled source chunk

  f32x4 acc[4][4];
#pragma unroll
  for (int mt = 0; mt < 4; ++mt)
#pragma unroll
    for (int nt = 0; nt < 4; ++nt) acc[mt][nt] = (f32x4){0.f, 0.f, 0.f, 0.f};

  const unsigned short* Abase = A + (size_t)bm * K;
  const unsigned short* Bbase = Bt + (size_t)bn * K;

  for (int k0 = 0; k0 < K; k0 += 64) {
    __syncthreads();
#pragma unroll
    for (int p = 0; p < 4; ++p) {
      const int r = p * 32 + wave * 8 + drow8;
      gl2lds16(Abase + (size_t)r * K + k0 + dsrc, As + r * 64 + dslot);
      gl2lds16(Bbase + (size_t)r * K + k0 + dsrc, Bs + r * 64 + dslot);
    }
    __syncthreads();

#pragma unroll
    for (int kk = 0; kk < 2; ++kk) {
      bf16x8 a[4], b[4];
#pragma unroll
      for (int mt = 0; mt < 4; ++mt)
        a[mt] = *(const bf16x8*)(
            As + (wm * 64 + mt * 16 + lo) * 64 + (((kk * 4 + g8) ^ lo7) * 8));
#pragma unroll
      for (int nt = 0; nt < 4; ++nt)
        b[nt] = *(const bf16x8*)(
            Bs + (wn * 64 + nt * 16 + lo) * 64 + (((kk * 4 + g8) ^ lo7) * 8));
#pragma unroll
      for (int mt = 0; mt < 4; ++mt)
#pragma unroll
        for (int nt = 0; nt < 4; ++nt)
          acc[mt][nt] = __builtin_amdgcn_mfma_f32_16x16x32_bf16(a[mt], b[nt], acc[mt][nt], 0, 0, 0);
    }
  }

  if (bn < 2 * C_DIM) {
    const float sc = (bn < C_DIM) ? 0.18033688011112042f : 1.0f;  // 0.125*log2e
#pragma unroll
    for (int nt = 0; nt < 4; ++nt) {
      const int n = bn + wn * 64 + nt * 16 + lo;
      const float bv = bias[n];
#pragma unroll
      for (int mt = 0; mt < 4; ++mt)
#pragma unroll
        for (int r = 0; r < 4; ++r) {
          const int m = bm + wm * 64 + mt * 16 + g8 * 4 + r;
          Cq[(size_t)m * C3 + n] = f2bf((acc[mt][nt][r] + bv) * sc);
        }
    }
  } else {
#pragma unroll
    for (int nt = 0; nt < 4; ++nt) {
      const int n = bn + wn * 64 + nt * 16 + lo;
      const float bv = bias[n];
      unsigned short* row = vTp + (size_t)(n - 2 * C_DIM) * T_SEQ;
#pragma unroll
      for (int mt = 0; mt < 4; ++mt) {
        const int mbase = (bm + wm * 64 + mt * 16 + g8 * 4) & ~31;
        bf16x4 o4;
#pragma unroll
        for (int r = 0; r < 4; ++r) o4[r] = (short)f2bf(acc[mt][nt][r] + bv);
        *(bf16x4*)(row + mbase + 8 * g8 + 4 * (mt & 1)) = o4;
      }
    }
  }
}

// ---------------------------------------------------------------------------
// gemm2: bf16 MFMA GEMM, B^T input, fp32 out.
// ---------------------------------------------------------------------------
__global__ __launch_bounds__(256) void gemm_bt_mfma(
    const unsigned short* __restrict__ A, const unsigned short* __restrict__ Bt,
    const float* __restrict__ bias, float* __restrict__ C,
    int M, int N, int K) {
  __shared__ unsigned short As[128 * 64];
  __shared__ unsigned short Bs[128 * 64];
  const int tid = threadIdx.x;
  const int wave = tid >> 6, lane = tid & 63;
  const int lo = lane & 15, g8 = lane >> 4;
  const int lo7 = lo & 7;
  const int wm = wave >> 1, wn = wave & 1;
  const int bm = blockIdx.y * 128, bn = blockIdx.x * 128;
  const int drow8 = lane >> 3;
  const int dslot = (lane & 7) * 8;
  const int dsrc = ((lane & 7) ^ drow8) * 8;

  f32x4 acc[4][4];
#pragma unroll
  for (int mt = 0; mt < 4; ++mt)
#pragma unroll
    for (int nt = 0; nt < 4; ++nt) acc[mt][nt] = (f32x4){0.f, 0.f, 0.f, 0.f};

  const unsigned short* Abase = A + (size_t)bm * K;
  const unsigned short* Bbase = Bt + (size_t)bn * K;

  for (int k0 = 0; k0 < K; k0 += 64) {
    __syncthreads();
#pragma unroll
    for (int p = 0; p < 4; ++p) {
      const int r = p * 32 + wave * 8 + drow8;
      gl2lds16(Abase + (size_t)r * K + k0 + dsrc, As + r * 64 + dslot);
      gl2lds16(Bbase + (size_t)r * K + k0 + dsrc, Bs + r * 64 + dslot);
    }
    __syncthreads();

#pragma unroll
    for (int kk = 0; kk < 2; ++kk) {
      bf16x8 a[4], b[4];
#pragma unroll
      for (int mt = 0; mt < 4; ++mt)
        a[mt] = *(const bf16x8*)(
            As + (wm * 64 + mt * 16 + lo) * 64 + (((kk * 4 + g8) ^ lo7) * 8));
#pragma unroll
      for (int nt = 0; nt < 4; ++nt)
        b[nt] = *(const bf16x8*)(
            Bs + (wn * 64 + nt * 16 + lo) * 64 + (((kk * 4 + g8) ^ lo7) * 8));
#pragma unroll
      for (int mt = 0; mt < 4; ++mt)
#pragma unroll
        for (int nt = 0; nt < 4; ++nt)
          acc[mt][nt] = __builtin_amdgcn_mfma_f32_16x16x32_bf16(a[mt], b[nt], acc[mt][nt], 0, 0, 0);
    }
  }

#pragma unroll
  for (int nt = 0; nt < 4; ++nt) {
    const int n = bn + wn * 64 + nt * 16 + lo;
    const float bv = bias[n];
#pragma unroll
    for (int mt = 0; mt < 4; ++mt)
#pragma unroll
      for (int r = 0; r < 4; ++r) {
        const int m = bm + wm * 64 + mt * 16 + g8 * 4 + r;
        C[(size_t)m * N + n] = acc[mt][nt][r] + bv;
      }
  }
}

// ---------------------------------------------------------------------------
// flash v18b: QBLK=256, 512 threads (8 waves x 32 q-rows), KVBLK=64,
// triple-buffer + counted vmcnt. 16 q-blocks/head; q-block qt has
// n = 4qt+4 k-tiles, chunked at D=12: nc(qt) = qt/3+1, 51 recs/head,
// 612 blocks (480 full-12 launched first, then 8-tails, then 4-tails).
// launch_bounds(512,2): no VGPR cap (R20's (512,6) forced a spill cascade).
// ---------------------------------------------------------------------------
#define NRECH  51                          // records per head
#define PO_REC (256 * 64)
#define KSTEP  (64 * C3)                   // shorts per k-tile (K stream)

__device__ inline int s_pref(int qt) {     // S(qt) = sum_{q<qt} (q/3+1)
  const int A = qt / 3, B = qt - 3 * A;
  return qt + 3 * A * (A - 1) / 2 + A * B;
}

__global__ __launch_bounds__(512, 2) void flash_attn_qb256(
    const unsigned short* __restrict__ qkv,   // [T][2304] bf16 (Qs,K valid)
    const unsigned short* __restrict__ vTp,   // [768][T] bf16, k-permuted
    float* __restrict__ Po, float* __restrict__ Pl) {
  __shared__ unsigned short Ks[3][64 * 64];
  __shared__ unsigned short Vs[3][64 * 64];

  // longest-first decode of blockIdx.x -> (h, qt, c, k0, T)
  const int u = blockIdx.x;
  int h, qt, c, k0, T;
  if (u < 480) {                       // full-12 chunks
    h = u / 40;
    const int w40 = u % 40;
    qt = 2; c = 0;
    for (int q = 15; q >= 2; --q) {
      const int A = q / 3, B = q - 3 * A;          // F12(q) = sum floor(m/3)
      const int F = 3 * A * (A - 1) / 2 + A * (B + 1);
      if (w40 >= F) { qt = q; c = w40 - F; break; }
    }
    k0 = 12 * c; T = 12;
  } else if (u < 540) {                // 8-tails (qt = 3e+1)
    const int v = u - 480; h = v / 5; const int e = v % 5;
    qt = 3 * e + 1; c = e; k0 = 12 * e; T = 8;
  } else {                             // 4-tails (qt = 3e)
    const int v = u - 540; h = v / 6; const int e = v % 6;
    qt = 3 * e; c = e; k0 = 12 * e; T = 4;
  }
  const int rec = h * NRECH + s_pref(qt) + c;
  const int qt4 = 4 * qt;              // first diagonal k-tile

  const int tid = threadIdx.x;
  const int w = tid >> 6;              // 0..7
  const int lane = tid & 63;
  const int lo = lane & 15;
  const int g = lane >> 4;
  const int lo7 = lo & 7;

  const unsigned short* Kg = qkv + C_DIM + h * HD;           // row stride C3
  const unsigned short* Vg = vTp + (size_t)(h * HD) * T_SEQ; // row stride T_SEQ

  const int drow = tid >> 3;                    // 0..63 (full tile row)
  const int dslot = (tid & 7) * 8;
  const int dsrc = ((tid & 7) ^ (drow & 7)) * 8;

  // Q B-frags: 2 q-halves x 2 d-halves (Q pre-scaled in gemm1). Issued
  // before the DMAs; in-order vmcnt retirement => vmcnt(2) covers them.
  const int qw0 = w * 32 + lo;                  // local q-row, + qh*16
  bf16x8 qb[2][2];
#pragma unroll
  for (int qh = 0; qh < 2; ++qh)
#pragma unroll
    for (int dh = 0; dh < 2; ++dh)
      qb[qh][dh] = *(const bf16x8*)(
          qkv + (size_t)(qt * 256 + qw0 + qh * 16) * C3 + h * HD + dh * 32 + g * 8);

  // stride-increment DMA pointers (one K + one V DMA per thread per tile)
  const unsigned short* pK = Kg + (size_t)(k0 * 64 + drow) * C3 + dsrc;
  const unsigned short* pV = Vg + (size_t)drow * T_SEQ + k0 * 64 + dsrc;

  auto stage = [&](int buf) __attribute__((always_inline)) {
    gl2lds16(pK, Ks[buf] + drow * 64 + dslot);
    gl2lds16(pV, Vs[buf] + drow * 64 + dslot);
    pK += KSTEP; pV += 64;
  };

  bf16x8 onesb;
#pragma unroll
  for (int e = 0; e < 8; ++e) onesb[e] = (short)0x3F80;  // bf16 1.0

  // prologue: distance-2 pipeline (T >= 4 always)
  stage(0);
  stage(1);
  asm volatile("s_waitcnt vmcnt(2)" ::: "memory");  // qb + tile0 done
  __builtin_amdgcn_s_barrier();

  f32x4 o_acc[2][4];
  f32x4 lacc[2];
#pragma unroll
  for (int qh = 0; qh < 2; ++qh) {
    lacc[qh] = (f32x4){0.f, 0.f, 0.f, 0.f};
#pragma unroll
    for (int dt = 0; dt < 4; ++dt) o_acc[qh][dt] = (f32x4){0.f, 0.f, 0.f, 0.f};
  }

  int ic = 0, iw = 2;
  int ktc = k0;
  for (int t = 0; t < T; ++t) {
    if (t + 2 < T) stage(iw);
    const unsigned short* Kc = Ks[ic];
    const unsigned short* Vc = Vs[ic];

    // St = K @ Q^T  (scale folded into Q); K-frag shared by both q-halves
    f32x4 st[2][4];
#pragma unroll
    for (int qh = 0; qh < 2; ++qh)
#pragma unroll
      for (int mt = 0; mt < 4; ++mt) st[qh][mt] = (f32x4){0.f, 0.f, 0.f, 0.f};
    __builtin_amdgcn_s_setprio(1);
#pragma unroll
    for (int mt = 0; mt < 4; ++mt)
#pragma unroll
      for (int dh = 0; dh < 2; ++dh) {
        bf16x8 a = *(const bf16x8*)(
            Kc + (mt * 16 + lo) * 64 + (((dh * 4 + g) ^ lo7) * 8));
#pragma unroll
        for (int qh = 0; qh < 2; ++qh)
          st[qh][mt] = __builtin_amdgcn_mfma_f32_16x16x32_bf16(
              a, qb[qh][dh], st[qh][mt], 0, 0, 0);
      }
    __builtin_amdgcn_s_setprio(0);

    // causal mask: diagonal k-tiles (ktc in [4qt, 4qt+3])
    if (ktc >= qt4) {
      const int mb = (ktc - qt4) * 64;
#pragma unroll
      for (int qh = 0; qh < 2; ++qh) {
        const int qr = qw0 + qh * 16;
#pragma unroll
        for (int mt = 0; mt < 4; ++mt)
#pragma unroll
          for (int r = 0; r < 4; ++r)
            if (mb + mt * 16 + g * 4 + r > qr) st[qh][mt][r] = -1e30f;
      }
    }

    // no-max softmax: e = exp2(s)  (per-element trunc pack — proven codegen)
    bf16x8 pt[2][2];
#pragma unroll
    for (int qh = 0; qh < 2; ++qh)
#pragma unroll
      for (int kh = 0; kh < 2; ++kh)
#pragma unroll
        for (int jj = 0; jj < 4; ++jj) {
          float e0 = EXP2F(st[qh][kh * 2][jj]);
          float e1 = EXP2F(st[qh][kh * 2 + 1][jj]);
          pt[qh][kh][jj] = (short)f2bf_trunc(e0);
          pt[qh][kh][4 + jj] = (short)f2bf_trunc(e1);
        }

    __builtin_amdgcn_s_setprio(1);
    // l via ones-row MFMA (K-permutation invariant)
#pragma unroll
    for (int qh = 0; qh < 2; ++qh) {
      lacc[qh] = __builtin_amdgcn_mfma_f32_16x16x32_bf16(onesb, pt[qh][0], lacc[qh], 0, 0, 0);
      lacc[qh] = __builtin_amdgcn_mfma_f32_16x16x32_bf16(onesb, pt[qh][1], lacc[qh], 0, 0, 0);
    }
    // O^T += V^T @ P^T ; V-frag shared by both q-halves
#pragma unroll
    for (int dt = 0; dt < 4; ++dt)
#pragma unroll
      for (int kh = 0; kh < 2; ++kh) {
        bf16x8 av = *(const bf16x8*)(
            Vc + (dt * 16 + lo) * 64 + (((kh * 4 + g) ^ lo7) * 8));
#pragma unroll
        for (int qh = 0; qh < 2; ++qh)
          o_acc[qh][dt] = __builtin_amdgcn_mfma_f32_16x16x32_bf16(
              av, pt[qh][kh], o_acc[qh][dt], 0, 0, 0);
      }
    __builtin_amdgcn_s_setprio(0);

    // counted wait: tile t+1 complete; tile t+2's 2 DMAs stay in flight
    if (t + 2 < T)
      asm volatile("s_waitcnt vmcnt(2)" ::: "memory");
    else
      asm volatile("s_waitcnt vmcnt(0)" ::: "memory");
    __builtin_amdgcn_s_barrier();

    ic = (ic == 2) ? 0 : ic + 1;
    iw = (iw == 2) ? 0 : iw + 1;
    ++ktc;
  }

  // flush: unnormalized fp32 partials to record `rec`
  float* PoS = Po + (size_t)rec * PO_REC;
#pragma unroll
  for (int qh = 0; qh < 2; ++qh)
#pragma unroll
    for (int dt = 0; dt < 4; ++dt)
      *(f32x4*)(PoS + (qw0 + qh * 16) * 64 + dt * 16 + g * 4) = o_acc[qh][dt];
  if (g == 0) {
    float* PlS = Pl + (size_t)rec * 256;
#pragma unroll
    for (int qh = 0; qh < 2; ++qh) PlS[qw0 + qh * 16] = lacc[qh][0];
  }
}

// ---------------------------------------------------------------------------
// combine: out = (sum of recs) / (sum of l) -> bf16 [4096][768]
// records for (h,qt) are contiguous: [h*51 + S(qt), +nc) with nc = qt/3+1
// ---------------------------------------------------------------------------
__global__ __launch_bounds__(256) void combine_qb256(
    const float* __restrict__ Po, const float* __restrict__ Pl,
    unsigned short* __restrict__ out) {
  const int bid = blockIdx.x;          // 192 = NH*16
  const int h = bid >> 4, qt = bid & 15;
  const int nc = qt / 3 + 1;
  const int rec0 = h * NRECH + s_pref(qt);
  const int tid = threadIdx.x;
  const int q0 = tid >> 2;             // 0..63
  const int c0 = (tid & 3) * 16;
#pragma unroll
  for (int qq = 0; qq < 4; ++qq) {
    const int q = qq * 64 + q0;
    float l = 0.f;
    f32x4 acc[4];
#pragma unroll
    for (int e = 0; e < 4; ++e) acc[e] = (f32x4){0.f, 0.f, 0.f, 0.f};
    for (int c = 0; c < nc; ++c) {
      const size_t base = (size_t)(rec0 + c);
      l += Pl[base * 256 + q];
      const float* P = Po + base * PO_REC + q * 64 + c0;
#pragma unroll
      for (int e = 0; e < 4; ++e) acc[e] += *(const f32x4*)(P + e * 4);
    }
    const float inv = 1.0f / l;
    unsigned short ob[16];
#pragma unroll
    for (int e = 0; e < 4; ++e)
#pragma unroll
      for (int r = 0; r < 4; ++r) ob[e * 4 + r] = f2bf(acc[e][r] * inv);
    unsigned short* op = out + (size_t)(qt * 256 + q) * C_DIM + h * 64 + c0;
    *(uint4*)op = *(uint4*)ob;
    *(uint4*)(op + 8) = *(uint4*)(ob + 8);
  }
}

// ---------------------------------------------------------------------------
extern "C" void kernel_launch(void* const* d_in, const int* in_sizes, int n_in,
                              void* d_out, int out_size, void* d_ws, size_t ws_size,
                              hipStream_t stream) {
  const float* x      = (const float*)d_in[0];
  const float* w_qkv  = (const float*)d_in[1];
  const float* b_qkv  = (const float*)d_in[2];
  const float* w_proj = (const float*)d_in[3];
  const float* b_proj = (const float*)d_in[4];
  float* out = (float*)d_out;

  unsigned short* xb     = (unsigned short*)d_ws;               // [4096,768]
  unsigned short* wqkvT  = xb + (size_t)T_SEQ * C_DIM;          // [2304,768]
  unsigned short* wprojT = wqkvT + (size_t)C3 * C_DIM;          // [768,768]
  unsigned short* qkv    = wprojT + (size_t)C_DIM * C_DIM;      // [4096,2304]
  unsigned short* vTp    = qkv + (size_t)T_SEQ * C3;            // [768,4096]
  unsigned short* attnb  = xb;  // alias: xb is dead after gemm_qkv
  float* Po = (float*)(vTp + (size_t)C_DIM * T_SEQ);            // 612 recs fp32
  float* Pl = Po + (size_t)NH * NRECH * PO_REC;                 // 612*256 fp32

  prep_fused<<<NB_CONV + NB_TQKV + NB_TPROJ, 256, 0, stream>>>(
      x, w_qkv, w_proj, xb, wqkvT, wprojT);

  gemm_qkv<<<dim3(C3 / 128, T_SEQ / 128), 256, 0, stream>>>(
      xb, wqkvT, b_qkv, qkv, vTp, T_SEQ, C3, C_DIM);

  flash_attn_qb256<<<612, 512, 0, stream>>>(qkv, vTp, Po, Pl);

  combine_qb256<<<NH * 16, 256, 0, stream>>>(Po, Pl, attnb);

  gemm_bt_mfma<<<dim3(C_DIM / 128, T_SEQ / 128), 256, 0, stream>>>(
      attnb, wprojT, b_proj, out, T_SEQ, C_DIM, C_DIM);
}

// Round 8
// 174.642 us; speedup vs baseline: 1.7235x; 1.0524x over previous
//
#include <hip/hip_runtime.h>
#include <hip/hip_bf16.h>

// CausalSelfAttention  B=1, T=4096, C=768, H=12, hd=64
// Round 22: R21 post-mortem: flash 45.8us (spill fixed, concurrency theory
//   confirmed) but totals show the NON-flash rest is ~138us and stable —
//   gemm_qkv at K=768 on the 128^2 2-barrier structure sits at ~320-350 TF
//   (shape-curve) ~= 41-45us, just under flash in top-5. Fix: 256x128-tile
//   gemm_qkv, 512 threads / 8 waves (the R21-proven block shape), 48KB LDS:
//   2x MFMA per barrier-pair, -25% staging DMAs. Per-output math/epilogues
//   bit-identical (incl. k-permuted vTp write). All other kernels untouched.

#define T_SEQ 4096
#define C_DIM 768
#define C3    2304
#define NH    12
#define HD    64

typedef __attribute__((ext_vector_type(8))) short bf16x8;
typedef __attribute__((ext_vector_type(4))) short bf16x4;
typedef __attribute__((ext_vector_type(4))) float f32x4;

__device__ inline unsigned short f2bf(float f) {
  union { float f; unsigned u; } v; v.f = f;
  unsigned r = v.u + 0x7fff + ((v.u >> 16) & 1);  // RTNE
  return (unsigned short)(r >> 16);
}
__device__ inline unsigned short f2bf_trunc(float f) {
  union { float f; unsigned u; } v; v.f = f;
  return (unsigned short)(v.u >> 16);  // truncate: fine for P >= 0
}

__device__ inline void gl2lds16(const void* g, void* l) {
  __builtin_amdgcn_global_load_lds(
      (const __attribute__((address_space(1))) unsigned int*)g,
      (__attribute__((address_space(3))) unsigned int*)l, 16, 0, 0);
}

#if __has_builtin(__builtin_amdgcn_exp2f)
#define EXP2F(x) __builtin_amdgcn_exp2f(x)
#else
#define EXP2F(x) exp2f(x)
#endif

// ---------------------------------------------------------------------------
// fused prep: conv x->bf16 | transpose w_qkv | transpose w_proj
// ---------------------------------------------------------------------------
#define NB_CONV  (T_SEQ * C_DIM / 2048)          // 1536
#define NB_TQKV  ((C3 / 32) * (C_DIM / 32))      // 1728
#define NB_TPROJ ((C_DIM / 32) * (C_DIM / 32))   // 576

__global__ __launch_bounds__(256) void prep_fused(
    const float* __restrict__ x, const float* __restrict__ w_qkv,
    const float* __restrict__ w_proj, unsigned short* __restrict__ xb,
    unsigned short* __restrict__ wqkvT, unsigned short* __restrict__ wprojT) {
  __shared__ float t[32][33];
  const int b = blockIdx.x;
  const int tid = threadIdx.x;

  if (b < NB_CONV) {
    int i = (b * 256 + tid) * 8;
    float4 v0 = *(const float4*)(x + i);
    float4 v1 = *(const float4*)(x + i + 4);
    unsigned short o[8] = {f2bf(v0.x), f2bf(v0.y), f2bf(v0.z), f2bf(v0.w),
                           f2bf(v1.x), f2bf(v1.y), f2bf(v1.z), f2bf(v1.w)};
    *(uint4*)(xb + i) = *(uint4*)o;
    return;
  }
  const float* in;
  unsigned short* outT;
  int R, Cc, bi;
  if (b < NB_CONV + NB_TQKV) {
    in = w_qkv; outT = wqkvT; R = C_DIM; Cc = C3; bi = b - NB_CONV;
  } else {
    in = w_proj; outT = wprojT; R = C_DIM; Cc = C_DIM; bi = b - NB_CONV - NB_TQKV;
  }
  const int tx = tid & 31, ty = tid >> 5;
  const int c0 = (bi % (Cc / 32)) * 32, r0 = (bi / (Cc / 32)) * 32;
#pragma unroll
  for (int i = 0; i < 4; ++i) {
    int r = ty + i * 8;
    t[r][tx] = in[(size_t)(r0 + r) * Cc + c0 + tx];
  }
  __syncthreads();
#pragma unroll
  for (int i = 0; i < 4; ++i) {
    int c = ty + i * 8;
    outT[(size_t)(c0 + c) * R + r0 + tx] = f2bf(t[tx][c]);
  }
}

// ---------------------------------------------------------------------------
// gemm1: qkv = xb @ wqkvT^T + b_qkv; V blocks write k-permuted vTp directly.
// Q columns (n < 768) pre-scaled by 0.125*log2(e).
// R22: 256x128 tile, 512 threads (8 waves as 4M x 2N), 48KB LDS. Per-wave
// fragment math and epilogues identical to the 128^2 version.
// ---------------------------------------------------------------------------
__global__ __launch_bounds__(512) void gemm_qkv(
    const unsigned short* __restrict__ A, const unsigned short* __restrict__ Bt,
    const float* __restrict__ bias, unsigned short* __restrict__ Cq,
    unsigned short* __restrict__ vTp, int M, int N, int K) {
  __shared__ unsigned short As[256 * 64];
  __shared__ unsigned short Bs[128 * 64];
  const int tid = threadIdx.x;
  const int wave = tid >> 6, lane = tid & 63;
  const int lo = lane & 15, g8 = lane >> 4;
  const int lo7 = lo & 7;
  const int wm = wave >> 1, wn = wave & 1;     // 4 x 2 wave grid
  const int bm = blockIdx.y * 256, bn = blockIdx.x * 128;
  const int drow = tid >> 3;                   // 0..63
  const int dslot = (tid & 7) * 8;
  const int dsrc = ((tid & 7) ^ (drow & 7)) * 8;  // p*64 keeps row&7 invariant

  f32x4 acc[4][4];
#pragma unroll
  for (int mt = 0; mt < 4; ++mt)
#pragma unroll
    for (int nt = 0; nt < 4; ++nt) acc[mt][nt] = (f32x4){0.f, 0.f, 0.f, 0.f};

  const unsigned short* Abase = A + (size_t)bm * K;
  const unsigned short* Bbase = Bt + (size_t)bn * K;

  for (int k0 = 0; k0 < K; k0 += 64) {
    __syncthreads();
#pragma unroll
    for (int p = 0; p < 4; ++p) {
      const int r = p * 64 + drow;
      gl2lds16(Abase + (size_t)r * K + k0 + dsrc, As + r * 64 + dslot);
    }
#pragma unroll
    for (int p = 0; p < 2; ++p) {
      const int r = p * 64 + drow;
      gl2lds16(Bbase + (size_t)r * K + k0 + dsrc, Bs + r * 64 + dslot);
    }
    __syncthreads();

#pragma unroll
    for (int kk = 0; kk < 2; ++kk) {
      bf16x8 a[4], b[4];
#pragma unroll
      for (int mt = 0; mt < 4; ++mt)
        a[mt] = *(const bf16x8*)(
            As + (wm * 64 + mt * 16 + lo) * 64 + (((kk * 4 + g8) ^ lo7) * 8));
#pragma unroll
      for (int nt = 0; nt < 4; ++nt)
        b[nt] = *(const bf16x8*)(
            Bs + (wn * 64 + nt * 16 + lo) * 64 + (((kk * 4 + g8) ^ lo7) * 8));
#pragma unroll
      for (int mt = 0; mt < 4; ++mt)
#pragma unroll
        for (int nt = 0; nt < 4; ++nt)
          acc[mt][nt] = __builtin_amdgcn_mfma_f32_16x16x32_bf16(a[mt], b[nt], acc[mt][nt], 0, 0, 0);
    }
  }

  if (bn < 2 * C_DIM) {
    const float sc = (bn < C_DIM) ? 0.18033688011112042f : 1.0f;  // 0.125*log2e
#pragma unroll
    for (int nt = 0; nt < 4; ++nt) {
      const int n = bn + wn * 64 + nt * 16 + lo;
      const float bv = bias[n];
#pragma unroll
      for (int mt = 0; mt < 4; ++mt)
#pragma unroll
        for (int r = 0; r < 4; ++r) {
          const int m = bm + wm * 64 + mt * 16 + g8 * 4 + r;
          Cq[(size_t)m * C3 + n] = f2bf((acc[mt][nt][r] + bv) * sc);
        }
    }
  } else {
#pragma unroll
    for (int nt = 0; nt < 4; ++nt) {
      const int n = bn + wn * 64 + nt * 16 + lo;
      const float bv = bias[n];
      unsigned short* row = vTp + (size_t)(n - 2 * C_DIM) * T_SEQ;
#pragma unroll
      for (int mt = 0; mt < 4; ++mt) {
        const int mbase = (bm + wm * 64 + mt * 16 + g8 * 4) & ~31;
        bf16x4 o4;
#pragma unroll
        for (int r = 0; r < 4; ++r) o4[r] = (short)f2bf(acc[mt][nt][r] + bv);
        *(bf16x4*)(row + mbase + 8 * g8 + 4 * (mt & 1)) = o4;
      }
    }
  }
}

// ---------------------------------------------------------------------------
// gemm2: bf16 MFMA GEMM, B^T input, fp32 out. (unchanged 128^2)
// ---------------------------------------------------------------------------
__global__ __launch_bounds__(256) void gemm_bt_mfma(
    const unsigned short* __restrict__ A, const unsigned short* __restrict__ Bt,
    const float* __restrict__ bias, float* __restrict__ C,
    int M, int N, int K) {
  __shared__ unsigned short As[128 * 64];
  __shared__ unsigned short Bs[128 * 64];
  const int tid = threadIdx.x;
  const int wave = tid >> 6, lane = tid & 63;
  const int lo = lane & 15, g8 = lane >> 4;
  const int lo7 = lo & 7;
  const int wm = wave >> 1, wn = wave & 1;
  const int bm = blockIdx.y * 128, bn = blockIdx.x * 128;
  const int drow8 = lane >> 3;
  const int dslot = (lane & 7) * 8;
  const int dsrc = ((lane & 7) ^ drow8) * 8;

  f32x4 acc[4][4];
#pragma unroll
  for (int mt = 0; mt < 4; ++mt)
#pragma unroll
    for (int nt = 0; nt < 4; ++nt) acc[mt][nt] = (f32x4){0.f, 0.f, 0.f, 0.f};

  const unsigned short* Abase = A + (size_t)bm * K;
  const unsigned short* Bbase = Bt + (size_t)bn * K;

  for (int k0 = 0; k0 < K; k0 += 64) {
    __syncthreads();
#pragma unroll
    for (int p = 0; p < 4; ++p) {
      const int r = p * 32 + wave * 8 + drow8;
      gl2lds16(Abase + (size_t)r * K + k0 + dsrc, As + r * 64 + dslot);
      gl2lds16(Bbase + (size_t)r * K + k0 + dsrc, Bs + r * 64 + dslot);
    }
    __syncthreads();

#pragma unroll
    for (int kk = 0; kk < 2; ++kk) {
      bf16x8 a[4], b[4];
#pragma unroll
      for (int mt = 0; mt < 4; ++mt)
        a[mt] = *(const bf16x8*)(
            As + (wm * 64 + mt * 16 + lo) * 64 + (((kk * 4 + g8) ^ lo7) * 8));
#pragma unroll
      for (int nt = 0; nt < 4; ++nt)
        b[nt] = *(const bf16x8*)(
            Bs + (wn * 64 + nt * 16 + lo) * 64 + (((kk * 4 + g8) ^ lo7) * 8));
#pragma unroll
      for (int mt = 0; mt < 4; ++mt)
#pragma unroll
        for (int nt = 0; nt < 4; ++nt)
          acc[mt][nt] = __builtin_amdgcn_mfma_f32_16x16x32_bf16(a[mt], b[nt], acc[mt][nt], 0, 0, 0);
    }
  }

#pragma unroll
  for (int nt = 0; nt < 4; ++nt) {
    const int n = bn + wn * 64 + nt * 16 + lo;
    const float bv = bias[n];
#pragma unroll
    for (int mt = 0; mt < 4; ++mt)
#pragma unroll
      for (int r = 0; r < 4; ++r) {
        const int m = bm + wm * 64 + mt * 16 + g8 * 4 + r;
        C[(size_t)m * N + n] = acc[mt][nt][r] + bv;
      }
  }
}

// ---------------------------------------------------------------------------
// flash v18b (unchanged from R21): QBLK=256, 512 threads, KVBLK=64,
// triple-buffer + counted vmcnt, D=12 split-k, 612 blocks.
// ---------------------------------------------------------------------------
#define NRECH  51                          // records per head
#define PO_REC (256 * 64)
#define KSTEP  (64 * C3)                   // shorts per k-tile (K stream)

__device__ inline int s_pref(int qt) {     // S(qt) = sum_{q<qt} (q/3+1)
  const int A = qt / 3, B = qt - 3 * A;
  return qt + 3 * A * (A - 1) / 2 + A * B;
}

__global__ __launch_bounds__(512, 2) void flash_attn_qb256(
    const unsigned short* __restrict__ qkv,   // [T][2304] bf16 (Qs,K valid)
    const unsigned short* __restrict__ vTp,   // [768][T] bf16, k-permuted
    float* __restrict__ Po, float* __restrict__ Pl) {
  __shared__ unsigned short Ks[3][64 * 64];
  __shared__ unsigned short Vs[3][64 * 64];

  // longest-first decode of blockIdx.x -> (h, qt, c, k0, T)
  const int u = blockIdx.x;
  int h, qt, c, k0, T;
  if (u < 480) {                       // full-12 chunks
    h = u / 40;
    const int w40 = u % 40;
    qt = 2; c = 0;
    for (int q = 15; q >= 2; --q) {
      const int A = q / 3, B = q - 3 * A;          // F12(q) = sum floor(m/3)
      const int F = 3 * A * (A - 1) / 2 + A * (B + 1);
      if (w40 >= F) { qt = q; c = w40 - F; break; }
    }
    k0 = 12 * c; T = 12;
  } else if (u < 540) {                // 8-tails (qt = 3e+1)
    const int v = u - 480; h = v / 5; const int e = v % 5;
    qt = 3 * e + 1; c = e; k0 = 12 * e; T = 8;
  } else {                             // 4-tails (qt = 3e)
    const int v = u - 540; h = v / 6; const int e = v % 6;
    qt = 3 * e; c = e; k0 = 12 * e; T = 4;
  }
  const int rec = h * NRECH + s_pref(qt) + c;
  const int qt4 = 4 * qt;              // first diagonal k-tile

  const int tid = threadIdx.x;
  const int w = tid >> 6;              // 0..7
  const int lane = tid & 63;
  const int lo = lane & 15;
  const int g = lane >> 4;
  const int lo7 = lo & 7;

  const unsigned short* Kg = qkv + C_DIM + h * HD;           // row stride C3
  const unsigned short* Vg = vTp + (size_t)(h * HD) * T_SEQ; // row stride T_SEQ

  const int drow = tid >> 3;                    // 0..63 (full tile row)
  const int dslot = (tid & 7) * 8;
  const int dsrc = ((tid & 7) ^ (drow & 7)) * 8;

  // Q B-frags: 2 q-halves x 2 d-halves (Q pre-scaled in gemm1). Issued
  // before the DMAs; in-order vmcnt retirement => vmcnt(2) covers them.
  const int qw0 = w * 32 + lo;                  // local q-row, + qh*16
  bf16x8 qb[2][2];
#pragma unroll
  for (int qh = 0; qh < 2; ++qh)
#pragma unroll
    for (int dh = 0; dh < 2; ++dh)
      qb[qh][dh] = *(const bf16x8*)(
          qkv + (size_t)(qt * 256 + qw0 + qh * 16) * C3 + h * HD + dh * 32 + g * 8);

  // stride-increment DMA pointers (one K + one V DMA per thread per tile)
  const unsigned short* pK = Kg + (size_t)(k0 * 64 + drow) * C3 + dsrc;
  const unsigned short* pV = Vg + (size_t)drow * T_SEQ + k0 * 64 + dsrc;

  auto stage = [&](int buf) __attribute__((always_inline)) {
    gl2lds16(pK, Ks[buf] + drow * 64 + dslot);
    gl2lds16(pV, Vs[buf] + drow * 64 + dslot);
    pK += KSTEP; pV += 64;
  };

  bf16x8 onesb;
#pragma unroll
  for (int e = 0; e < 8; ++e) onesb[e] = (short)0x3F80;  // bf16 1.0

  // prologue: distance-2 pipeline (T >= 4 always)
  stage(0);
  stage(1);
  asm volatile("s_waitcnt vmcnt(2)" ::: "memory");  // qb + tile0 done
  __builtin_amdgcn_s_barrier();

  f32x4 o_acc[2][4];
  f32x4 lacc[2];
#pragma unroll
  for (int qh = 0; qh < 2; ++qh) {
    lacc[qh] = (f32x4){0.f, 0.f, 0.f, 0.f};
#pragma unroll
    for (int dt = 0; dt < 4; ++dt) o_acc[qh][dt] = (f32x4){0.f, 0.f, 0.f, 0.f};
  }

  int ic = 0, iw = 2;
  int ktc = k0;
  for (int t = 0; t < T; ++t) {
    if (t + 2 < T) stage(iw);
    const unsigned short* Kc = Ks[ic];
    const unsigned short* Vc = Vs[ic];

    // St = K @ Q^T  (scale folded into Q); K-frag shared by both q-halves
    f32x4 st[2][4];
#pragma unroll
    for (int qh = 0; qh < 2; ++qh)
#pragma unroll
      for (int mt = 0; mt < 4; ++mt) st[qh][mt] = (f32x4){0.f, 0.f, 0.f, 0.f};
    __builtin_amdgcn_s_setprio(1);
#pragma unroll
    for (int mt = 0; mt < 4; ++mt)
#pragma unroll
      for (int dh = 0; dh < 2; ++dh) {
        bf16x8 a = *(const bf16x8*)(
            Kc + (mt * 16 + lo) * 64 + (((dh * 4 + g) ^ lo7) * 8));
#pragma unroll
        for (int qh = 0; qh < 2; ++qh)
          st[qh][mt] = __builtin_amdgcn_mfma_f32_16x16x32_bf16(
              a, qb[qh][dh], st[qh][mt], 0, 0, 0);
      }
    __builtin_amdgcn_s_setprio(0);

    // causal mask: diagonal k-tiles (ktc in [4qt, 4qt+3])
    if (ktc >= qt4) {
      const int mb = (ktc - qt4) * 64;
#pragma unroll
      for (int qh = 0; qh < 2; ++qh) {
        const int qr = qw0 + qh * 16;
#pragma unroll
        for (int mt = 0; mt < 4; ++mt)
#pragma unroll
          for (int r = 0; r < 4; ++r)
            if (mb + mt * 16 + g * 4 + r > qr) st[qh][mt][r] = -1e30f;
      }
    }

    // no-max softmax: e = exp2(s)  (per-element trunc pack — proven codegen)
    bf16x8 pt[2][2];
#pragma unroll
    for (int qh = 0; qh < 2; ++qh)
#pragma unroll
      for (int kh = 0; kh < 2; ++kh)
#pragma unroll
        for (int jj = 0; jj < 4; ++jj) {
          float e0 = EXP2F(st[qh][kh * 2][jj]);
          float e1 = EXP2F(st[qh][kh * 2 + 1][jj]);
          pt[qh][kh][jj] = (short)f2bf_trunc(e0);
          pt[qh][kh][4 + jj] = (short)f2bf_trunc(e1);
        }

    __builtin_amdgcn_s_setprio(1);
    // l via ones-row MFMA (K-permutation invariant)
#pragma unroll
    for (int qh = 0; qh < 2; ++qh) {
      lacc[qh] = __builtin_amdgcn_mfma_f32_16x16x32_bf16(onesb, pt[qh][0], lacc[qh], 0, 0, 0);
      lacc[qh] = __builtin_amdgcn_mfma_f32_16x16x32_bf16(onesb, pt[qh][1], lacc[qh], 0, 0, 0);
    }
    // O^T += V^T @ P^T ; V-frag shared by both q-halves
#pragma unroll
    for (int dt = 0; dt < 4; ++dt)
#pragma unroll
      for (int kh = 0; kh < 2; ++kh) {
        bf16x8 av = *(const bf16x8*)(
            Vc + (dt * 16 + lo) * 64 + (((kh * 4 + g) ^ lo7) * 8));
#pragma unroll
        for (int qh = 0; qh < 2; ++qh)
          o_acc[qh][dt] = __builtin_amdgcn_mfma_f32_16x16x32_bf16(
              av, pt[qh][kh], o_acc[qh][dt], 0, 0, 0);
      }
    __builtin_amdgcn_s_setprio(0);

    // counted wait: tile t+1 complete; tile t+2's 2 DMAs stay in flight
    if (t + 2 < T)
      asm volatile("s_waitcnt vmcnt(2)" ::: "memory");
    else
      asm volatile("s_waitcnt vmcnt(0)" ::: "memory");
    __builtin_amdgcn_s_barrier();

    ic = (ic == 2) ? 0 : ic + 1;
    iw = (iw == 2) ? 0 : iw + 1;
    ++ktc;
  }

  // flush: unnormalized fp32 partials to record `rec`
  float* PoS = Po + (size_t)rec * PO_REC;
#pragma unroll
  for (int qh = 0; qh < 2; ++qh)
#pragma unroll
    for (int dt = 0; dt < 4; ++dt)
      *(f32x4*)(PoS + (qw0 + qh * 16) * 64 + dt * 16 + g * 4) = o_acc[qh][dt];
  if (g == 0) {
    float* PlS = Pl + (size_t)rec * 256;
#pragma unroll
    for (int qh = 0; qh < 2; ++qh) PlS[qw0 + qh * 16] = lacc[qh][0];
  }
}

// ---------------------------------------------------------------------------
// combine: out = (sum of recs) / (sum of l) -> bf16 [4096][768]
// records for (h,qt) are contiguous: [h*51 + S(qt), +nc) with nc = qt/3+1
// ---------------------------------------------------------------------------
__global__ __launch_bounds__(256) void combine_qb256(
    const float* __restrict__ Po, const float* __restrict__ Pl,
    unsigned short* __restrict__ out) {
  const int bid = blockIdx.x;          // 192 = NH*16
  const int h = bid >> 4, qt = bid & 15;
  const int nc = qt / 3 + 1;
  const int rec0 = h * NRECH + s_pref(qt);
  const int tid = threadIdx.x;
  const int q0 = tid >> 2;             // 0..63
  const int c0 = (tid & 3) * 16;
#pragma unroll
  for (int qq = 0; qq < 4; ++qq) {
    const int q = qq * 64 + q0;
    float l = 0.f;
    f32x4 acc[4];
#pragma unroll
    for (int e = 0; e < 4; ++e) acc[e] = (f32x4){0.f, 0.f, 0.f, 0.f};
    for (int c = 0; c < nc; ++c) {
      const size_t base = (size_t)(rec0 + c);
      l += Pl[base * 256 + q];
      const float* P = Po + base * PO_REC + q * 64 + c0;
#pragma unroll
      for (int e = 0; e < 4; ++e) acc[e] += *(const f32x4*)(P + e * 4);
    }
    const float inv = 1.0f / l;
    unsigned short ob[16];
#pragma unroll
    for (int e = 0; e < 4; ++e)
#pragma unroll
      for (int r = 0; r < 4; ++r) ob[e * 4 + r] = f2bf(acc[e][r] * inv);
    unsigned short* op = out + (size_t)(qt * 256 + q) * C_DIM + h * 64 + c0;
    *(uint4*)op = *(uint4*)ob;
    *(uint4*)(op + 8) = *(uint4*)(ob + 8);
  }
}

// ---------------------------------------------------------------------------
extern "C" void kernel_launch(void* const* d_in, const int* in_sizes, int n_in,
                              void* d_out, int out_size, void* d_ws, size_t ws_size,
                              hipStream_t stream) {
  const float* x      = (const float*)d_in[0];
  const float* w_qkv  = (const float*)d_in[1];
  const float* b_qkv  = (const float*)d_in[2];
  const float* w_proj = (const float*)d_in[3];
  const float* b_proj = (const float*)d_in[4];
  float* out = (float*)d_out;

  unsigned short* xb     = (unsigned short*)d_ws;               // [4096,768]
  unsigned short* wqkvT  = xb + (size_t)T_SEQ * C_DIM;          // [2304,768]
  unsigned short* wprojT = wqkvT + (size_t)C3 * C_DIM;          // [768,768]
  unsigned short* qkv    = wprojT + (size_t)C_DIM * C_DIM;      // [4096,2304]
  unsigned short* vTp    = qkv + (size_t)T_SEQ * C3;            // [768,4096]
  unsigned short* attnb  = xb;  // alias: xb is dead after gemm_qkv
  float* Po = (float*)(vTp + (size_t)C_DIM * T_SEQ);            // 612 recs fp32
  float* Pl = Po + (size_t)NH * NRECH * PO_REC;                 // 612*256 fp32

  prep_fused<<<NB_CONV + NB_TQKV + NB_TPROJ, 256, 0, stream>>>(
      x, w_qkv, w_proj, xb, wqkvT, wprojT);

  gemm_qkv<<<dim3(C3 / 128, T_SEQ / 256), 512, 0, stream>>>(
      xb, wqkvT, b_qkv, qkv, vTp, T_SEQ, C3, C_DIM);

  flash_attn_qb256<<<612, 512, 0, stream>>>(qkv, vTp, Po, Pl);

  combine_qb256<<<NH * 16, 256, 0, stream>>>(Po, Pl, attnb);

  gemm_bt_mfma<<<dim3(C_DIM / 128, T_SEQ / 128), 256, 0, stream>>>(
      attnb, wprojT, b_proj, out, T_SEQ, C_DIM, C_DIM);
}